// Round 4
// baseline (10083.975 us; speedup 1.0000x reference)
//
#include <hip/hip_runtime.h>
#include <hip/hip_bf16.h>
#include <stdint.h>

// LSTM persistent kernel, round 4.
//   grid = 256 WGs (1/CU), block = 512 threads = 8 waves.
//   WG (rb,cb): rows rb*32..+32 (rb<8), h-cols cb*32..+32 (cb<32).
//   Wave wv: gate g = wv&3, k-half hf = wv>>2; weight B-frags resident.
//   ROUND-4 CHANGE: the 32 rows are split into TWO independent 16-row
//   streams (A = rows +0..16, B = +16..32) with separate barriers/counters.
//   Streams alternate per step, so stream A's h-exchange latency (store
//   drain -> L3 visibility -> detect -> sc1 load) hides under stream B's
//   compute and vice-versa. (Rounds 2/3 showed the barrier *contention* was
//   irrelevant: per-rb split gave -4%; all pipes <12% busy -> the exposed
//   serial latency chain with zero independent resident work is the cost.)
//   Also: h slab stored in LDS in A-FRAGMENT order so every ds_read/ds_write
//   is `const + lane*16B` (conflict-free; round-3 layout cost 1.7e8 conflict
//   cycles).

typedef __bf16 bf16x8 __attribute__((ext_vector_type(8)));
typedef float  f32x4  __attribute__((ext_vector_type(4)));
typedef uint32_t u32x4 __attribute__((ext_vector_type(4)));

union U8 { bf16x8 v; __bf16 e[8]; };
union PK { uint32_t u; __bf16 e[2]; };

#define MFMA16(a,b,c) __builtin_amdgcn_mfma_f32_16x16x32_bf16((a),(b),(c),0,0,0)

// device-coherent 16B load: bypass L1/L2, read from coherence point (L3)
#define GLOADX4(dst, base, OFF)                                              \
  asm volatile("global_load_dwordx4 %0, %1, off offset:" #OFF " sc0 sc1"     \
               : "=v"(dst) : "v"(base))
// device-coherent 4B store: write through to coherence point
#define GSTORE1(base, val)                                                   \
  asm volatile("global_store_dword %0, %1, off sc0 sc1"                      \
               :: "v"(base), "v"(val) : "memory")
#define WAIT_VM0() asm volatile("s_waitcnt vmcnt(0)" ::: "memory")

__global__ __launch_bounds__(512, 2) void lstm_persist(
    const float* __restrict__ x,
    const float* __restrict__ Wii, const float* __restrict__ Whi, const float* __restrict__ bi,
    const float* __restrict__ Wif, const float* __restrict__ Whf, const float* __restrict__ bfv,
    const float* __restrict__ Wig, const float* __restrict__ Whg, const float* __restrict__ bgv,
    const float* __restrict__ Wio, const float* __restrict__ Who, const float* __restrict__ bov,
    float* __restrict__ out,
    uint32_t* __restrict__ hbuf,   // ws: 2 * 256*1024 bf16 ping-pong (as dwords)
    uint32_t* cnts)                // ws: 16 counters (rb,stream), 1 KB apart
{
  constexpr int S = 512;
  // LDS: two 16-row h slabs in FRAG-MAJOR layout [ (hf*16+kt)*256 + lane*4 ]
  // (32 KB each), pre-act exchange (16 KB), h-store transpose (~1 KB).
  __shared__ uint32_t hfrag[2][8192];
  __shared__ float    Pbuf[4096];
  __shared__ __bf16   transb[16 * 34];

  const int wg   = blockIdx.x;
  const int rb   = wg >> 5;      // 8 row blocks of 32 rows
  const int cb   = wg & 31;      // 32 col blocks of 32 h-cols
  const int tid  = threadIdx.x;
  const int wv   = tid >> 6;     // 8 waves
  const int g    = wv & 3;       // gate
  const int hf   = wv >> 2;      // k-half
  const int lane = tid & 63;
  const int l15  = lane & 15;
  const int quad = lane >> 4;

  const float* Wi_g = (g == 0) ? Wii : (g == 1) ? Wif : (g == 2) ? Wig : Wio;
  const float* Wh_g = (g == 0) ? Whi : (g == 1) ? Whf : (g == 2) ? Whg : Who;

  // ---- one-time: weight B-fragments into registers (bf16) ----
  // B-frag layout: lane holds B[k][n], n = lane&15, k = quad*8 + j.
  bf16x8 hB[16][2];   // Wh k-tiles for this half (k = hf*512 .. +512)
  bf16x8 xB[8][2];    // Wi k-tiles for this half (k = hf*256 .. +256)
  #pragma unroll
  for (int nt = 0; nt < 2; ++nt) {
    const int col = cb * 32 + nt * 16 + l15;
    #pragma unroll
    for (int kt = 0; kt < 16; ++kt) {
      U8 u;
      #pragma unroll
      for (int j = 0; j < 8; ++j)
        u.e[j] = (__bf16)Wh_g[(size_t)(hf * 512 + kt * 32 + quad * 8 + j) * 1024 + col];
      hB[kt][nt] = u.v;
    }
    #pragma unroll
    for (int kt = 0; kt < 8; ++kt) {
      U8 u;
      #pragma unroll
      for (int j = 0; j < 8; ++j)
        u.e[j] = (__bf16)Wi_g[(size_t)(hf * 256 + kt * 32 + quad * 8 + j) * 1024 + col];
      xB[kt][nt] = u.v;
    }
  }

  // ---- reducer role: ONE cell per thread per stream ----
  const int nt_r  = (tid >> 4) & 1;
  const int reg_r = (tid >> 5) & 3;
  const int q_r   = (tid >> 7) & 3;
  const int rcol  = nt_r * 16 + l15 - (quad >> 2) * 0 + 0;  // col_l
  const int col_l = nt_r * 16 + (tid & 15);
  const int row_l = q_r * 4 + reg_r;           // 0..15 within stream slab
  const int gcol  = cb * 32 + col_l;
  const float bias_i = bi[gcol], bias_f = bfv[gcol];
  const float bias_g = bgv[gcol], bias_o = bov[gcol];
  float cc[2] = {0.f, 0.f};                    // cell state per stream
  (void)rcol;

  // ---- h-slab writer role: r = tid&15 (row), j = tid>>4 (k-chunk group) ----
  const int wr_r = tid & 15;
  const int wr_j = tid >> 4;                   // 0..31
  // LDS frag position for chunk c=j+32i: tile=(hf*16+kt), pos=(c&3)*16 + r
  const int wbase = ((wr_j & 3) * 16 + wr_r) * 4 + (wr_j >> 2) * 256;

  // ---- h-store role (tid<256): 1 dword (2 cols) ----
  const int srow = (tid >> 4) & 15, scd = tid & 15;

  uint32_t* const hb0 = hbuf;
  uint32_t* const hb1 = hbuf + 131072;

  __syncthreads();

  for (int t = 0; t < S; ++t) {
    #pragma unroll
    for (int s = 0; s < 2; ++s) {
      const int rbase = rb * 32 + s * 16;
      uint32_t* const mycnt = cnts + (rb * 2 + s) * 256;

      // ---- x loads + cvt (independent of barrier) ----
      const float* px = x + (size_t)(rbase + l15) * (512 * 512)
                          + (size_t)t * 512 + hf * 256 + quad * 8;
      U8 xA[8];
      #pragma unroll
      for (int kt = 0; kt < 8; ++kt) {
        const float4 u0 = *(const float4*)(px + kt * 32);
        const float4 u1 = *(const float4*)(px + kt * 32 + 4);
        xA[kt].e[0]=(__bf16)u0.x; xA[kt].e[1]=(__bf16)u0.y;
        xA[kt].e[2]=(__bf16)u0.z; xA[kt].e[3]=(__bf16)u0.w;
        xA[kt].e[4]=(__bf16)u1.x; xA[kt].e[5]=(__bf16)u1.y;
        xA[kt].e[6]=(__bf16)u1.z; xA[kt].e[7]=(__bf16)u1.w;
      }

      // ---- stream barrier: partners' h(s,t) stores visible? ----
      if (tid == 0) {
        const uint32_t target = (uint32_t)t * 32u;
        while (__hip_atomic_load(mycnt, __ATOMIC_RELAXED, __HIP_MEMORY_SCOPE_AGENT) < target)
          __builtin_amdgcn_s_sleep(1);
      }
      __syncthreads();

      // ---- issue coherent h loads (4 x 16B per thread) ----
      const uint32_t* hsrc = ((t & 1) ? hb1 : hb0)
                             + (size_t)(rbase + wr_r) * 512 + wr_j * 4;
      u32x4 h0, h1, h2, h3;
      GLOADX4(h0, hsrc, 0);
      GLOADX4(h1, hsrc, 512);
      GLOADX4(h2, hsrc, 1024);
      GLOADX4(h3, hsrc, 1536);

      // ---- x-MFMA while h loads are in flight ----
      f32x4 a0 = {0,0,0,0}, a1 = {0,0,0,0};
      #pragma unroll
      for (int kt = 0; kt < 8; ++kt) {
        a0 = MFMA16(xA[kt].v, xB[kt][0], a0);
        a1 = MFMA16(xA[kt].v, xB[kt][1], a1);
      }

      WAIT_VM0();
      {
        uint32_t* hw = &hfrag[s][0] + wbase;
        *(u32x4*)(hw +    0) = h0;   // i=0: hf0, kt=j>>2
        *(u32x4*)(hw + 2048) = h1;   // i=1: hf0, kt=j>>2+8
        *(u32x4*)(hw + 4096) = h2;   // i=2: hf1, kt=j>>2
        *(u32x4*)(hw + 6144) = h3;   // i=3: hf1, kt=j>>2+8
      }
      __syncthreads();

      // ---- h-MFMA: 16 k-tiles, frag-major reads (conflict-free) ----
      const uint32_t* hr = &hfrag[s][0] + hf * 16 * 256 + lane * 4;
      #pragma unroll
      for (int kt = 0; kt < 16; ++kt) {
        const bf16x8 A = *(const bf16x8*)(hr + kt * 256);
        a0 = MFMA16(A, hB[kt][0], a0);
        a1 = MFMA16(A, hB[kt][1], a1);
      }

      // ---- exchange pre-acts: slot = wv*2+nt, pos = lane ----
      *(f32x4*)&Pbuf[(wv * 2 + 0) * 256 + lane * 4] = a0;
      *(f32x4*)&Pbuf[(wv * 2 + 1) * 256 + lane * 4] = a1;
      __syncthreads();

      // ---- reduce halves, activations, cell update (1 cell/thread) ----
      const int po = (q_r * 16 + (tid & 15)) * 4 + reg_r;
      const float pi = Pbuf[(0 + nt_r) * 256 + po] + Pbuf[( 8 + nt_r) * 256 + po] + bias_i;
      const float pf = Pbuf[(2 + nt_r) * 256 + po] + Pbuf[(10 + nt_r) * 256 + po] + bias_f;
      const float pg = Pbuf[(4 + nt_r) * 256 + po] + Pbuf[(12 + nt_r) * 256 + po] + bias_g;
      const float pob= Pbuf[(6 + nt_r) * 256 + po] + Pbuf[(14 + nt_r) * 256 + po] + bias_o;

      const float gi = __builtin_amdgcn_rcpf(1.f + __expf(-pi));
      const float gf = __builtin_amdgcn_rcpf(1.f + __expf(-pf));
      const float gg = 2.f * __builtin_amdgcn_rcpf(1.f + __expf(-2.f * pg)) - 1.f;
      const float go = __builtin_amdgcn_rcpf(1.f + __expf(-pob));
      const float cn = gi * gg + gf * cc[s];
      cc[s] = cn;
      const float tc = 2.f * __builtin_amdgcn_rcpf(1.f + __expf(-2.f * cn)) - 1.f;
      const float hn = go * tc;
      transb[row_l * 34 + col_l] = (__bf16)hn;
      if (t == S - 1) {
        out[(size_t)(rbase + row_l) * 1024 + gcol] = hn;           // h_T
        out[262144 + (size_t)(rbase + row_l) * 1024 + gcol] = cn;  // c_T
      }
      __syncthreads();

      // ---- coherent h store (tid<256: 1 dword) ----
      if (tid < 256) {
        PK pk;
        pk.e[0] = transb[srow * 34 + scd * 2];
        pk.e[1] = transb[srow * 34 + scd * 2 + 1];
        uint32_t* dst = ((t & 1) ? hb0 : hb1)
                        + (size_t)(rbase + srow) * 512 + cb * 16 + scd;
        GSTORE1(dst, pk.u);
      }
      WAIT_VM0();            // h stores at the coherence point
      __syncthreads();       // whole WG drained
      if (tid == 0)
        __hip_atomic_fetch_add(mycnt, 1u, __ATOMIC_RELAXED, __HIP_MEMORY_SCOPE_AGENT);
    }
  }
}

extern "C" void kernel_launch(void* const* d_in, const int* in_sizes, int n_in,
                              void* d_out, int out_size, void* d_ws, size_t ws_size,
                              hipStream_t stream) {
  const float* xp  = (const float*)d_in[0];
  const float* Wii = (const float*)d_in[1];
  const float* Whi = (const float*)d_in[2];
  const float* bi  = (const float*)d_in[3];
  const float* Wif = (const float*)d_in[4];
  const float* Whf = (const float*)d_in[5];
  const float* bf_ = (const float*)d_in[6];
  const float* Wig = (const float*)d_in[7];
  const float* Whg = (const float*)d_in[8];
  const float* bg  = (const float*)d_in[9];
  const float* Wio = (const float*)d_in[10];
  const float* Who = (const float*)d_in[11];
  const float* bo  = (const float*)d_in[12];
  float* out = (float*)d_out;

  uint32_t* hbuf = (uint32_t*)d_ws;
  uint32_t* cnts = (uint32_t*)((char*)d_ws + 2u * 262144u * sizeof(__bf16));

  // zero h ping-pong + 16 stream counters (ws re-poisoned before every launch)
  hipMemsetAsync(d_ws, 0, 2u * 262144u * sizeof(__bf16) + 16u * 1024u, stream);

  lstm_persist<<<dim3(256), dim3(512), 0, stream>>>(
      xp, Wii, Whi, bi, Wif, Whf, bf_, Wig, Whg, bg, Wio, Who, bo,
      out, hbuf, cnts);
}